// Round 5
// baseline (27.250 us; speedup 1.0000x reference)
//
#include <hip/hip_runtime.h>
#include <hip/hip_bf16.h>

// Poly2d as bf16 MFMA GEMM, register-resident Q.
// out[o,p] = sum_{c,kl} W[o,c,kl] * Q[c,kl,p], kl in [0,56):
//   kl 0..8 linear (s_j*(F0j+Fj0)), 9..17 squares (s_j^2*Fjj),
//   18..53 pairs (s_i*s_j*(Fij+Fji)), 54 const-1 (F00 + bias @c==0), 55 zero.
// MFMA 32x32x16 B-operand: lane (hf=l>>5, n=l&31) holds B[k=hf*8+e][n].
// k-slot -> (channel,kl) bijection chosen so each lane's slots use only
// channels cA = 2*pair+hf, cB = 2*pair+1-hf with compile-time kl:
//   step st<4 : ch = cA, kl = 16*st + e
//   step st>=4: ch = cB, kl = 16*(st-4)+8+e
// W2 is written with the same permutation (prep_w2), so Q fragments are
// computed directly in VGPRs -- no Q staging, no barriers in the main loop.

typedef __attribute__((ext_vector_type(8))) short short8;
typedef __attribute__((ext_vector_type(16))) float f32x16;

#define NCH  64
#define NOUT 64

__device__ constexpr signed char TI[56] = {
  0,0,0,0,0,0,0,0,0,
  1,2,3,4,5,6,7,8,9,
  1,1,1,1,1,1,1,1,
  2,2,2,2,2,2,2,
  3,3,3,3,3,3,
  4,4,4,4,4,
  5,5,5,5,
  6,6,6,
  7,7,
  8,
  0,0};
__device__ constexpr signed char TJ[56] = {
  1,2,3,4,5,6,7,8,9,
  1,2,3,4,5,6,7,8,9,
  2,3,4,5,6,7,8,9,
  3,4,5,6,7,8,9,
  4,5,6,7,8,9,
  5,6,7,8,9,
  6,7,8,9,
  7,8,9,
  8,9,
  9,
  0,0};

__device__ __forceinline__ unsigned short f2bf(float f) {
  __hip_bfloat16 h = __float2bfloat16(f);
  unsigned short u;
  __builtin_memcpy(&u, &h, 2);
  return u;
}

// prep_w2 v2: one block per channel pair (32 blocks). Stage F[:, 2p:2p+2]
// into LDS with coalesced float4 streams (51.2 KB), then compute the pair's
// W2 slice (7168 bf16 = 896 short8, CONTIGUOUS) with coalesced 16B stores.
// W2 flat layout: off = pair*7168 + st*1024 + hf*512 + o*8 + e   (shorts)
__global__ __launch_bounds__(256) void prep_w2(const float* __restrict__ F,
                                               const float* __restrict__ biases,
                                               unsigned short* __restrict__ W2) {
  const int pair = blockIdx.x;
  __shared__ float Fl[64 * 200];    // [o][ch_local*100 + i*10+j]
  __shared__ float bl[64];
  for (int t = threadIdx.x; t < 3200; t += 256) {
    int o = t / 50, r = t % 50;
    *(float4*)&Fl[o * 200 + r * 4] =
        *(const float4*)&F[((size_t)o * NCH + 2 * pair) * 100 + r * 4];
  }
  if (threadIdx.x < 64) bl[threadIdx.x] = biases[threadIdx.x];
  __syncthreads();
  for (int s = threadIdx.x; s < 896; s += 256) {   // short8 index in slice
    int o = s & 63, hf = (s >> 6) & 1, st = s >> 7;
    int chl = (st < 4) ? hf : 1 - hf;
    const float* base = &Fl[o * 200 + chl * 100];
    short8 v;
    #pragma unroll
    for (int e = 0; e < 8; ++e) {
      int kl = (st < 4) ? (16 * st + e) : (16 * (st - 4) + 8 + e);
      float w;
      if (kl < 54) {
        int i = TI[kl], j = TJ[kl];
        if (i == 0)      w = base[j] + base[j * 10];
        else if (i == j) w = base[i * 10 + j];
        else             w = base[i * 10 + j] + base[j * 10 + i];
      } else if (kl == 54) {
        w = base[0] + ((pair == 0 && chl == 0) ? bl[o] : 0.f);
      } else {
        w = 0.f;
      }
      v[e] = (short)f2bf(w);
    }
    *(short8*)&W2[(size_t)pair * 7168 + (size_t)s * 8] = v;
  }
}

// 256 blocks = (b, h); 512 threads = 8 waves; wave w owns channels [8w, 8w+8).
// LDS arena (136 KB), two phases (aliased):
//   phase 1 (xs): channel ci -> dwords [ci*216, ci*216+216): 3 rows x 72 cols,
//                 x[w] at col w+4; cols 0..3 / 68..71 zero halo. Wave-private.
//   phase 2 (R):  partials, row (g*64+p) stride 68 dwords, o contiguous.
__global__ __launch_bounds__(512, 2) void poly2d_mfma(
    const float* __restrict__ x, const unsigned short* __restrict__ W2,
    float* __restrict__ out) {
  const int b = blockIdx.x >> 6, h = blockIdx.x & 63;
  const int tid = threadIdx.x;
  const int lane = tid & 63, wave = tid >> 6;
  const int px = lane & 31, hf = lane >> 5;

  __shared__ float smem[34816];   // 139264 B

  // ---- stage this wave's 8 channels (vectorized, division-free) ----
  {
    const int r = lane >> 4, q = lane & 15;          // lanes 0..47: body quads
    const size_t xbase = ((size_t)b * NCH + wave * 8) * 4096;
    #pragma unroll
    for (int i = 0; i < 8; ++i) {
      float* ch0 = &smem[(wave * 8 + i) * 216];
      if (lane < 48) {
        int hh = h + r - 1;
        bool ok = (unsigned)hh < 64u;
        int hcl = ok ? hh : 0;                       // clamped (safe) address
        float4 v = *(const float4*)&x[xbase + (size_t)i * 4096 + hcl * 64 + (q << 2)];
        if (!ok) v = make_float4(0.f, 0.f, 0.f, 0.f);
        *(float4*)&ch0[r * 72 + 4 + (q << 2)] = v;
      } else if (lane < 54) {
        int rr = (lane - 48) >> 1, side = lane & 1;  // zero halo cols
        *(float4*)&ch0[rr * 72 + (side ? 68 : 0)] = make_float4(0.f, 0.f, 0.f, 0.f);
      }
    }
  }
  // no __syncthreads: staging is wave-private, ordered by lgkmcnt

  f32x16 a00, a01, a10, a11;
  #pragma unroll
  for (int r = 0; r < 16; ++r) { a00[r] = 0.f; a01[r] = 0.f; a10[r] = 0.f; a11[r] = 0.f; }

  #pragma unroll
  for (int stage = 0; stage < 4; ++stage) {
    const int cA = stage * 2 + hf;        // wave-local channel of this lane-half
    const int cB = cA ^ 1;

    // (1) issue ALL W2 loads for this stage first (L2 latency hides under
    //     the DS reads + product VALU below)
    const unsigned short* wb =
        W2 + (size_t)(wave * 4 + stage) * 7168 + hf * 512 + px * 8;
    short8 w0[7], w1[7];
    #pragma unroll
    for (int st = 0; st < 7; ++st) {
      w0[st] = *(const short8*)(wb + st * 1024);        // o 0..31
      w1[st] = *(const short8*)(wb + st * 1024 + 256);  // o 32..63
    }

    // (2) window DS reads (constant offsets -> ds_read2_b32 pairs)
    const float* rA = &smem[(wave * 8 + cA) * 216 + px];
    const float* rB = &smem[(wave * 8 + cB) * 216 + px];
    float sA0[9], sA1[9], sB0[9], sB1[9];
    #pragma unroll
    for (int r = 0; r < 3; ++r) {
      #pragma unroll
      for (int d = 0; d < 3; ++d) {
        sA0[r * 3 + d] = rA[r * 72 + 3 + d];
        sA1[r * 3 + d] = rA[r * 72 + 35 + d];
        sB0[r * 3 + d] = rB[r * 72 + 3 + d];
        sB1[r * 3 + d] = rB[r * 72 + 35 + d];
      }
    }

    // (3) products + MFMA, one pixel-half at a time (keeps P at 28 VGPR)
    #pragma unroll
    for (int half = 0; half < 2; ++half) {
      const float* sa = half ? sA1 : sA0;
      const float* sb = half ? sB1 : sB0;
      short8 P[7];
      #pragma unroll
      for (int g = 0; g < 7; ++g) {
        short8 pk;
        #pragma unroll
        for (int e = 0; e < 8; ++e) {
          const int kl = (g < 4) ? (16 * g + e) : (16 * (g - 4) + 8 + e);
          const float* s = (g < 4) ? sa : sb;
          float v;
          if (kl == 55)      v = 0.f;
          else if (kl == 54) v = 1.f;
          else if (kl < 9)   v = s[kl];
          else if (kl < 18)  { float t = s[kl - 9]; v = t * t; }
          else               v = s[TI[kl] - 1] * s[TJ[kl] - 1];
          pk[e] = (short)f2bf(v);
        }
        P[g] = pk;
      }
      if (half == 0) {
        #pragma unroll
        for (int st = 0; st < 7; ++st) {
          a00 = __builtin_amdgcn_mfma_f32_32x32x16_bf16(w0[st], P[st], a00, 0, 0, 0);
          a10 = __builtin_amdgcn_mfma_f32_32x32x16_bf16(w1[st], P[st], a10, 0, 0, 0);
        }
      } else {
        #pragma unroll
        for (int st = 0; st < 7; ++st) {
          a01 = __builtin_amdgcn_mfma_f32_32x32x16_bf16(w0[st], P[st], a01, 0, 0, 0);
          a11 = __builtin_amdgcn_mfma_f32_32x32x16_bf16(w1[st], P[st], a11, 0, 0, 0);
        }
      }
    }
  }

  // ---- single-round transposed reduction over the 8 split-K partials ----
  __syncthreads();               // all waves done with xs (arena reused as R)
  // D layout (m74/m101): col = lane&31, row = (r&3) + 8*(r>>2) + 4*hf.
  // R(g, p, o) at smem[(g*64+p)*68 + o]; acc block r=4B..4B+3 -> o contiguous.
  {
    float* base0 = &smem[(wave * 64 + px) * 68];        // p = px
    float* base1 = &smem[(wave * 64 + px + 32) * 68];   // p = px+32
    #pragma unroll
    for (int blk = 0; blk < 4; ++blk) {
      int ob = blk * 8 + 4 * hf;
      *(float4*)&base0[ob]      = make_float4(a00[blk*4], a00[blk*4+1], a00[blk*4+2], a00[blk*4+3]);
      *(float4*)&base0[ob + 32] = make_float4(a10[blk*4], a10[blk*4+1], a10[blk*4+2], a10[blk*4+3]);
      *(float4*)&base1[ob]      = make_float4(a01[blk*4], a01[blk*4+1], a01[blk*4+2], a01[blk*4+3]);
      *(float4*)&base1[ob + 32] = make_float4(a11[blk*4], a11[blk*4+1], a11[blk*4+2], a11[blk*4+3]);
    }
  }
  __syncthreads();
  {
    const int op = wave * 8;     // this wave's o-block; lane = pixel p
    float s8[8] = {0.f, 0.f, 0.f, 0.f, 0.f, 0.f, 0.f, 0.f};
    #pragma unroll
    for (int g = 0; g < 8; ++g) {
      const float* rg = &smem[(g * 64 + lane) * 68 + op];
      float4 u0 = *(const float4*)&rg[0];
      float4 u1 = *(const float4*)&rg[4];
      s8[0] += u0.x; s8[1] += u0.y; s8[2] += u0.z; s8[3] += u0.w;
      s8[4] += u1.x; s8[5] += u1.y; s8[6] += u1.z; s8[7] += u1.w;
    }
    const size_t obase = (((size_t)b * NOUT + op) * 64 + h) * 64 + lane;
    #pragma unroll
    for (int k = 0; k < 8; ++k)
      out[obase + (size_t)k * 4096] = s8[k];
  }
}

extern "C" void kernel_launch(void* const* d_in, const int* in_sizes, int n_in,
                              void* d_out, int out_size, void* d_ws, size_t ws_size,
                              hipStream_t stream) {
  const float* x       = (const float*)d_in[0];
  const float* filters = (const float*)d_in[1];
  const float* biases  = (const float*)d_in[2];
  float* out = (float*)d_out;
  unsigned short* W2 = (unsigned short*)d_ws;   // 229376 bf16 = 458752 B

  hipLaunchKernelGGL(prep_w2, dim3(32), dim3(256), 0, stream,
                     filters, biases, W2);
  hipLaunchKernelGGL(poly2d_mfma, dim3(256), dim3(512), 0, stream,
                     x, W2, out);
}

// Round 7
// 24.302 us; speedup vs baseline: 1.1213x; 1.1213x over previous
//
#include <hip/hip_runtime.h>
#include <hip/hip_bf16.h>

// Poly2d as bf16 MFMA GEMM, register-resident Q.
// out[o,p] = sum_{c,kl} W[o,c,kl] * Q[c,kl,p], kl in [0,56):
//   kl 0..8 linear (s_j*(F0j+Fj0)), 9..17 squares (s_j^2*Fjj),
//   18..53 pairs (s_i*s_j*(Fij+Fji)), 54 const-1 (F00 + bias @c==0), 55 zero.
// MFMA 32x32x16 B-operand: lane (hf=l>>5, n=l&31) holds B[k=hf*8+e][n].
// k-slot -> (channel,kl) bijection chosen so each lane's slots use only
// channels cA = 2*pair+hf, cB = 2*pair+1-hf with compile-time kl:
//   step st<4 : ch = cA, kl = 16*st + e
//   step st>=4: ch = cB, kl = 16*(st-4)+8+e
// W2 is written with the same permutation (prep_w2), so Q fragments are
// computed directly in VGPRs -- no Q staging, no barriers in the main loop.
//
// R7 = R6 with the prep_w2 staging-coverage bug fixed (400 float4 loads need
// a strided loop over 256 threads; R6's `if (t < 400)` left Fl rows for
// o8>=5 uninitialized -> absmax 1e3).

typedef __attribute__((ext_vector_type(8))) short short8;
typedef __attribute__((ext_vector_type(16))) float f32x16;

#define NCH  64
#define NOUT 64

__device__ constexpr signed char TI[56] = {
  0,0,0,0,0,0,0,0,0,
  1,2,3,4,5,6,7,8,9,
  1,1,1,1,1,1,1,1,
  2,2,2,2,2,2,2,
  3,3,3,3,3,3,
  4,4,4,4,4,
  5,5,5,5,
  6,6,6,
  7,7,
  8,
  0,0};
__device__ constexpr signed char TJ[56] = {
  1,2,3,4,5,6,7,8,9,
  1,2,3,4,5,6,7,8,9,
  2,3,4,5,6,7,8,9,
  3,4,5,6,7,8,9,
  4,5,6,7,8,9,
  5,6,7,8,9,
  6,7,8,9,
  7,8,9,
  8,9,
  9,
  0,0};

__device__ __forceinline__ unsigned short f2bf(float f) {
  __hip_bfloat16 h = __float2bfloat16(f);
  unsigned short u;
  __builtin_memcpy(&u, &h, 2);
  return u;
}

// prep_w2 v3.1: 256 blocks = (pair, o-octet). Stage F[og*8..+8, 2p:2p+2]
// (1600 floats = 400 float4, coalesced, STRIDED LOOP) into LDS, emit 112
// short8 (128B-contig groups of 8).
// W2 layout: pair*7168 + st*1024 + hf*512 + o*8 + e (shorts).
__global__ __launch_bounds__(256) void prep_w2(const float* __restrict__ F,
                                               const float* __restrict__ biases,
                                               unsigned short* __restrict__ W2) {
  const int pair = blockIdx.x >> 3, og = blockIdx.x & 7;
  __shared__ float Fl[8 * 200];     // [o8][chl*100 + i*10+j]
  __shared__ float bl[8];
  for (int t = threadIdx.x; t < 400; t += 256) {   // 400 float4 = 1600 floats
    int o8 = t / 50, r = t % 50;
    *(float4*)&Fl[o8 * 200 + r * 4] =
        *(const float4*)&F[(((size_t)(og * 8 + o8)) * NCH + 2 * pair) * 100 + r * 4];
  }
  if (threadIdx.x < 8) bl[threadIdx.x] = biases[og * 8 + threadIdx.x];
  __syncthreads();
  {
    int s = threadIdx.x;
    if (s < 112) {                  // o8 fast -> 8 consecutive short8 = 128B
      int o8 = s & 7, hf = (s >> 3) & 1, st = s >> 4;
      int chl = (st < 4) ? hf : 1 - hf;
      const float* base = &Fl[o8 * 200 + chl * 100];
      short8 v;
      #pragma unroll
      for (int e = 0; e < 8; ++e) {
        int kl = (st < 4) ? (16 * st + e) : (16 * (st - 4) + 8 + e);
        float w;
        if (kl < 54) {
          int i = TI[kl], j = TJ[kl];
          if (i == 0)      w = base[j] + base[j * 10];
          else if (i == j) w = base[i * 10 + j];
          else             w = base[i * 10 + j] + base[j * 10 + i];
        } else if (kl == 54) {
          w = base[0] + ((pair == 0 && chl == 0) ? bl[o8] : 0.f);
        } else {
          w = 0.f;
        }
        v[e] = (short)f2bf(w);
      }
      *(short8*)&W2[(size_t)pair * 7168 + (size_t)st * 1024 + hf * 512 +
                    (og * 8 + o8) * 8] = v;
    }
  }
}

// 512 blocks = (b, h, o-half); 512 threads = 8 waves; wave w owns channels
// [8w, 8w+8). LDS arena 72 KB (xs phase 55 KB / R phase 72 KB, aliased)
// -> 2 blocks/CU; VGPR target <=128 -> 4 waves/SIMD.
//   xs: channel ci -> dwords [ci*216, +216): 3 rows x 72 cols, x[w] at col
//       w+4, cols 0..3 / 68..71 zero halo. Wave-private (no barrier).
//   R:  partials, row (g*64+p) stride 36 dwords, o_local 0..31 contiguous.
__global__ __launch_bounds__(512, 4) void poly2d_mfma(
    const float* __restrict__ x, const unsigned short* __restrict__ W2,
    float* __restrict__ out) {
  const int oh = blockIdx.x & 1, bh = blockIdx.x >> 1;
  const int b = bh >> 6, h = bh & 63;
  const int tid = threadIdx.x;
  const int lane = tid & 63, wave = tid >> 6;
  const int px = lane & 31, hf = lane >> 5;

  __shared__ float smem[18432];   // 73728 B

  // ---- stage this wave's 8 channels (vectorized, division-free) ----
  {
    const int r = lane >> 4, q = lane & 15;          // lanes 0..47: body quads
    const size_t xbase = ((size_t)b * NCH + wave * 8) * 4096;
    #pragma unroll
    for (int i = 0; i < 8; ++i) {
      float* ch0 = &smem[(wave * 8 + i) * 216];
      if (lane < 48) {
        int hh = h + r - 1;
        bool ok = (unsigned)hh < 64u;
        int hcl = ok ? hh : 0;                       // clamped (safe) address
        float4 v = *(const float4*)&x[xbase + (size_t)i * 4096 + hcl * 64 + (q << 2)];
        if (!ok) v = make_float4(0.f, 0.f, 0.f, 0.f);
        *(float4*)&ch0[r * 72 + 4 + (q << 2)] = v;
      } else if (lane < 54) {
        int rr = (lane - 48) >> 1, side = lane & 1;  // zero halo cols
        *(float4*)&ch0[rr * 72 + (side ? 68 : 0)] = make_float4(0.f, 0.f, 0.f, 0.f);
      }
    }
  }
  // no __syncthreads: staging is wave-private, ordered by lgkmcnt

  f32x16 acc0, acc1;               // o-half tile x pixel-halves 0 / 1
  #pragma unroll
  for (int r = 0; r < 16; ++r) { acc0[r] = 0.f; acc1[r] = 0.f; }

  for (int stage = 0; stage < 4; ++stage) {
    const int cA = stage * 2 + hf;      // wave-local channel of this lane-half
    const int cB = cA ^ 1;

    // W2 loads for this stage, o-half only (7 short8 = 28 VGPR)
    const unsigned short* wb = W2 + (size_t)(wave * 4 + stage) * 7168 +
                               hf * 512 + oh * 256 + px * 8;
    short8 w[7];
    #pragma unroll
    for (int st = 0; st < 7; ++st)
      w[st] = *(const short8*)(wb + st * 1024);

    const float* rA = &smem[(wave * 8 + cA) * 216 + px];
    const float* rB = &smem[(wave * 8 + cB) * 216 + px];
    #pragma unroll
    for (int half = 0; half < 2; ++half) {
      const int c0 = half ? 35 : 3;     // window base col
      float sa[9], sb[9];
      #pragma unroll
      for (int r = 0; r < 3; ++r)
        #pragma unroll
        for (int d = 0; d < 3; ++d) {
          sa[r * 3 + d] = rA[r * 72 + c0 + d];
          sb[r * 3 + d] = rB[r * 72 + c0 + d];
        }
      #pragma unroll
      for (int st = 0; st < 7; ++st) {
        short8 pk;
        #pragma unroll
        for (int e = 0; e < 8; ++e) {
          const int kl = (st < 4) ? (16 * st + e) : (16 * (st - 4) + 8 + e);
          const float* s = (st < 4) ? sa : sb;
          float v;
          if (kl == 55)      v = 0.f;
          else if (kl == 54) v = 1.f;
          else if (kl < 9)   v = s[kl];
          else if (kl < 18)  { float t = s[kl - 9]; v = t * t; }
          else               v = s[TI[kl] - 1] * s[TJ[kl] - 1];
          pk[e] = (short)f2bf(v);
        }
        if (half == 0)
          acc0 = __builtin_amdgcn_mfma_f32_32x32x16_bf16(w[st], pk, acc0, 0, 0, 0);
        else
          acc1 = __builtin_amdgcn_mfma_f32_32x32x16_bf16(w[st], pk, acc1, 0, 0, 0);
      }
    }
  }

  // ---- single-round transposed reduction over the 8 split-K partials ----
  __syncthreads();               // all waves done with xs (arena reused as R)
  // D layout (m74/m101): col = lane&31 (= pixel), row = (r&3)+8*(r>>2)+4*hf
  // (= o_local). R(g, p, o_local) at smem[(g*64+p)*36 + o_local].
  {
    float* base0 = &smem[(wave * 64 + px) * 36];        // p = px
    float* base1 = &smem[(wave * 64 + px + 32) * 36];   // p = px+32
    #pragma unroll
    for (int blk = 0; blk < 4; ++blk) {
      int ob = blk * 8 + 4 * hf;
      *(float4*)&base0[ob] = make_float4(acc0[blk*4], acc0[blk*4+1], acc0[blk*4+2], acc0[blk*4+3]);
      *(float4*)&base1[ob] = make_float4(acc1[blk*4], acc1[blk*4+1], acc1[blk*4+2], acc1[blk*4+3]);
    }
  }
  __syncthreads();
  {
    const int p = tid & 63, oq = tid >> 6;   // o-quad 0..7
    float4 sum = make_float4(0.f, 0.f, 0.f, 0.f);
    #pragma unroll
    for (int g = 0; g < 8; ++g) {
      float4 v = *(const float4*)&smem[(g * 64 + p) * 36 + oq * 4];
      sum.x += v.x; sum.y += v.y; sum.z += v.z; sum.w += v.w;
    }
    const size_t obase =
        (((size_t)b * NOUT + oh * 32 + oq * 4) * 64 + h) * 64 + p;
    out[obase]           = sum.x;
    out[obase + 4096]    = sum.y;
    out[obase + 2*4096]  = sum.z;
    out[obase + 3*4096]  = sum.w;
  }
}

extern "C" void kernel_launch(void* const* d_in, const int* in_sizes, int n_in,
                              void* d_out, int out_size, void* d_ws, size_t ws_size,
                              hipStream_t stream) {
  const float* x       = (const float*)d_in[0];
  const float* filters = (const float*)d_in[1];
  const float* biases  = (const float*)d_in[2];
  float* out = (float*)d_out;
  unsigned short* W2 = (unsigned short*)d_ws;   // 229376 bf16 = 458752 B

  hipLaunchKernelGGL(prep_w2, dim3(256), dim3(256), 0, stream,
                     filters, biases, W2);
  hipLaunchKernelGGL(poly2d_mfma, dim3(512), dim3(512), 0, stream,
                     x, W2, out);
}

// Round 8
// 23.660 us; speedup vs baseline: 1.1517x; 1.0271x over previous
//
#include <hip/hip_runtime.h>
#include <hip/hip_bf16.h>

// Poly2d as bf16 MFMA GEMM, register-resident Q.
// out[o,p] = sum_{c,kl} W[o,c,kl] * Q[c,kl,p], kl in [0,56):
//   kl 0..8 linear (s_j*(F0j+Fj0)), 9..17 squares (s_j^2*Fjj),
//   18..53 pairs (s_i*s_j*(Fij+Fji)), 54 const-1 (F00 + bias @c==0), 55 zero.
// MFMA 32x32x16 B-operand: lane (hf=l>>5, n=l&31) holds B[k=hf*8+e][n].
// k-slot -> (channel,kl) bijection chosen so each lane's slots use only
// channels cA = 2*pair+hf, cB = 2*pair+1-hf with compile-time kl:
//   step st<4 : ch = cA, kl = 16*st + e
//   step st>=4: ch = cB, kl = 16*(st-4)+8+e
// W2 is written with the same permutation (prep_w2), so Q fragments are
// computed directly in VGPRs.
//
// R8: 16-wave blocks (kg 0..7 x o-half), 1024 thr, 256 blocks -> 4 waves/SIMD
// (R4/R7 had 2). W2 slices stay disjoint per wave (117 MB L2 total); x staged
// once per block; per-wave VGPR ~100 (acc 2 tiles). Reduction = R4's proven
// stride-68 arena, (kg,oh) disjoint slots, single round.

typedef __attribute__((ext_vector_type(8))) short short8;
typedef __attribute__((ext_vector_type(16))) float f32x16;

#define NCH  64
#define NOUT 64

__device__ constexpr signed char TI[56] = {
  0,0,0,0,0,0,0,0,0,
  1,2,3,4,5,6,7,8,9,
  1,1,1,1,1,1,1,1,
  2,2,2,2,2,2,2,
  3,3,3,3,3,3,
  4,4,4,4,4,
  5,5,5,5,
  6,6,6,
  7,7,
  8,
  0,0};
__device__ constexpr signed char TJ[56] = {
  1,2,3,4,5,6,7,8,9,
  1,2,3,4,5,6,7,8,9,
  2,3,4,5,6,7,8,9,
  3,4,5,6,7,8,9,
  4,5,6,7,8,9,
  5,6,7,8,9,
  6,7,8,9,
  7,8,9,
  8,9,
  9,
  0,0};

__device__ __forceinline__ unsigned short f2bf(float f) {
  __hip_bfloat16 h = __float2bfloat16(f);
  unsigned short u;
  __builtin_memcpy(&u, &h, 2);
  return u;
}

// prep_w2 v3.1 (proven R7): 256 blocks = (pair, o-octet). Coalesced float4
// stage of F[og*8..+8, 2p:2p+2] into LDS, emit 112 short8 contiguous.
// W2 layout: pair*7168 + st*1024 + hf*512 + o*8 + e (shorts).
__global__ __launch_bounds__(256) void prep_w2(const float* __restrict__ F,
                                               const float* __restrict__ biases,
                                               unsigned short* __restrict__ W2) {
  const int pair = blockIdx.x >> 3, og = blockIdx.x & 7;
  __shared__ float Fl[8 * 200];     // [o8][chl*100 + i*10+j]
  __shared__ float bl[8];
  for (int t = threadIdx.x; t < 400; t += 256) {   // 400 float4 = 1600 floats
    int o8 = t / 50, r = t % 50;
    *(float4*)&Fl[o8 * 200 + r * 4] =
        *(const float4*)&F[(((size_t)(og * 8 + o8)) * NCH + 2 * pair) * 100 + r * 4];
  }
  if (threadIdx.x < 8) bl[threadIdx.x] = biases[og * 8 + threadIdx.x];
  __syncthreads();
  {
    int s = threadIdx.x;
    if (s < 112) {                  // o8 fast -> 8 consecutive short8 = 128B
      int o8 = s & 7, hf = (s >> 3) & 1, st = s >> 4;
      int chl = (st < 4) ? hf : 1 - hf;
      const float* base = &Fl[o8 * 200 + chl * 100];
      short8 v;
      #pragma unroll
      for (int e = 0; e < 8; ++e) {
        int kl = (st < 4) ? (16 * st + e) : (16 * (st - 4) + 8 + e);
        float w;
        if (kl < 54) {
          int i = TI[kl], j = TJ[kl];
          if (i == 0)      w = base[j] + base[j * 10];
          else if (i == j) w = base[i * 10 + j];
          else             w = base[i * 10 + j] + base[j * 10 + i];
        } else if (kl == 54) {
          w = base[0] + ((pair == 0 && chl == 0) ? bl[o8] : 0.f);
        } else {
          w = 0.f;
        }
        v[e] = (short)f2bf(w);
      }
      *(short8*)&W2[(size_t)pair * 7168 + (size_t)st * 1024 + hf * 512 +
                    (og * 8 + o8) * 8] = v;
    }
  }
}

// 256 blocks = (b, h); 1024 threads = 16 waves = (kg 0..7, oh 0..1).
// Wave (kg,oh): channels [8kg, 8kg+8), outputs o in [oh*32, oh*32+32),
// all 64 px -> 2 acc tiles (32 VGPR). LDS arena 139 KB (xs 55 KB /
// reduction 139 KB, aliased): 1 block/CU, 4 waves/SIMD at <=128 VGPR.
//   xs: channel ci -> dwords [ci*216, +216): 3 rows x 72 cols, x[w] at col
//       w+4, cols 0..3 / 68..71 zero halo.
//   R:  partials, row (kg*64+p) stride 68 dwords, o 0..63 contiguous
//       (oh-waves fill disjoint o-halves).
__global__ __launch_bounds__(1024, 4) void poly2d_mfma(
    const float* __restrict__ x, const unsigned short* __restrict__ W2,
    float* __restrict__ out) {
  const int b = blockIdx.x >> 6, h = blockIdx.x & 63;
  const int tid = threadIdx.x;
  const int lane = tid & 63, wid = tid >> 6;
  const int kg = wid >> 1, oh = wid & 1;
  const int px = lane & 31, hf = lane >> 5;

  __shared__ float smem[34816];   // 139264 B

  // ---- stage: wave wid stages channels [4*wid, 4*wid+4) ----
  {
    const int r = lane >> 4, q = lane & 15;          // lanes 0..47: body quads
    const size_t xbase = ((size_t)b * NCH + wid * 4) * 4096;
    #pragma unroll
    for (int i = 0; i < 4; ++i) {
      float* ch0 = &smem[(wid * 4 + i) * 216];
      if (lane < 48) {
        int hh = h + r - 1;
        bool ok = (unsigned)hh < 64u;
        int hcl = ok ? hh : 0;                       // clamped (safe) address
        float4 v = *(const float4*)&x[xbase + (size_t)i * 4096 + hcl * 64 + (q << 2)];
        if (!ok) v = make_float4(0.f, 0.f, 0.f, 0.f);
        *(float4*)&ch0[r * 72 + 4 + (q << 2)] = v;
      } else if (lane < 54) {
        int rr = (lane - 48) >> 1, side = lane & 1;  // zero halo cols
        *(float4*)&ch0[rr * 72 + (side ? 68 : 0)] = make_float4(0.f, 0.f, 0.f, 0.f);
      }
    }
  }
  __syncthreads();                 // staging shared across waves now

  f32x16 acc0, acc1;               // px-half 0 / 1 (this wave's o-half)
  #pragma unroll
  for (int r = 0; r < 16; ++r) { acc0[r] = 0.f; acc1[r] = 0.f; }

  #pragma unroll
  for (int stage = 0; stage < 4; ++stage) {
    const int cA = kg * 8 + stage * 2 + hf;   // channel of this lane-half
    const int cB = cA ^ 1;

    // W2 loads for this stage, this wave's o-half (7 short8 = 28 VGPR),
    // shared across both px-halves -> W2 read exactly once per block total.
    const unsigned short* wb = W2 + (size_t)(kg * 4 + stage) * 7168 +
                               hf * 512 + oh * 256 + px * 8;
    short8 w[7];
    #pragma unroll
    for (int st = 0; st < 7; ++st)
      w[st] = *(const short8*)(wb + st * 1024);

    const float* rA = &smem[cA * 216 + px];
    const float* rB = &smem[cB * 216 + px];
    #pragma unroll
    for (int half = 0; half < 2; ++half) {
      const int c0 = half ? 35 : 3;     // window base col
      float sa[9], sb[9];
      #pragma unroll
      for (int r = 0; r < 3; ++r)
        #pragma unroll
        for (int d = 0; d < 3; ++d) {
          sa[r * 3 + d] = rA[r * 72 + c0 + d];
          sb[r * 3 + d] = rB[r * 72 + c0 + d];
        }
      #pragma unroll
      for (int st = 0; st < 7; ++st) {
        short8 pk;
        #pragma unroll
        for (int e = 0; e < 8; ++e) {
          const int kl = (st < 4) ? (16 * st + e) : (16 * (st - 4) + 8 + e);
          const float* s = (st < 4) ? sa : sb;
          float v;
          if (kl == 55)      v = 0.f;
          else if (kl == 54) v = 1.f;
          else if (kl < 9)   v = s[kl];
          else if (kl < 18)  { float t = s[kl - 9]; v = t * t; }
          else               v = s[TI[kl] - 1] * s[TJ[kl] - 1];
          pk[e] = (short)f2bf(v);
        }
        if (half == 0)
          acc0 = __builtin_amdgcn_mfma_f32_32x32x16_bf16(w[st], pk, acc0, 0, 0, 0);
        else
          acc1 = __builtin_amdgcn_mfma_f32_32x32x16_bf16(w[st], pk, acc1, 0, 0, 0);
      }
    }
  }

  // ---- single-round reduction over the 8 kg partials ----
  __syncthreads();               // all waves done with xs (arena reused as R)
  // D layout (m74/m101): col = lane&31 (= pixel), row = (r&3)+8*(r>>2)+4*hf
  // (= o_local). R(kg, p, o) at smem[(kg*64+p)*68 + o], o = oh*32 + o_local.
  {
    float* base0 = &smem[(kg * 64 + px) * 68 + oh * 32];        // p = px
    float* base1 = &smem[(kg * 64 + px + 32) * 68 + oh * 32];   // p = px+32
    #pragma unroll
    for (int blk = 0; blk < 4; ++blk) {
      int ob = blk * 8 + 4 * hf;
      *(float4*)&base0[ob] = make_float4(acc0[blk*4], acc0[blk*4+1], acc0[blk*4+2], acc0[blk*4+3]);
      *(float4*)&base1[ob] = make_float4(acc1[blk*4], acc1[blk*4+1], acc1[blk*4+2], acc1[blk*4+3]);
    }
  }
  __syncthreads();
  {
    const int p = tid & 63, oq = tid >> 6;   // o-quad 0..15
    float4 sum = make_float4(0.f, 0.f, 0.f, 0.f);
    #pragma unroll
    for (int g = 0; g < 8; ++g) {
      float4 v = *(const float4*)&smem[(g * 64 + p) * 68 + oq * 4];
      sum.x += v.x; sum.y += v.y; sum.z += v.z; sum.w += v.w;
    }
    const size_t obase = (((size_t)b * NOUT + oq * 4) * 64 + h) * 64 + p;
    out[obase]          = sum.x;
    out[obase + 4096]   = sum.y;
    out[obase + 2*4096] = sum.z;
    out[obase + 3*4096] = sum.w;
  }
}

extern "C" void kernel_launch(void* const* d_in, const int* in_sizes, int n_in,
                              void* d_out, int out_size, void* d_ws, size_t ws_size,
                              hipStream_t stream) {
  const float* x       = (const float*)d_in[0];
  const float* filters = (const float*)d_in[1];
  const float* biases  = (const float*)d_in[2];
  float* out = (float*)d_out;
  unsigned short* W2 = (unsigned short*)d_ws;   // 229376 bf16 = 458752 B

  hipLaunchKernelGGL(prep_w2, dim3(256), dim3(256), 0, stream,
                     filters, biases, W2);
  hipLaunchKernelGGL(poly2d_mfma, dim3(256), dim3(1024), 0, stream,
                     x, W2, out);
}

// Round 9
// 22.165 us; speedup vs baseline: 1.2294x; 1.0675x over previous
//
#include <hip/hip_runtime.h>
#include <hip/hip_bf16.h>

// Poly2d as bf16 MFMA GEMM, register-resident Q.
// out[o,p] = sum_{c,kl} W[o,c,kl] * Q[c,kl,p], kl in [0,56):
//   kl 0..8 linear (s_j*(F0j+Fj0)), 9..17 squares (s_j^2*Fjj),
//   18..53 pairs (s_i*s_j*(Fij+Fji)), 54 const-1 (F00 + bias @c==0), 55 zero.
// MFMA 32x32x16 B-operand: lane (hf=l>>5, n=l&31) holds B[k=hf*8+e][n].
// k-slot -> (channel,kl) bijection chosen so each lane's slots use only
// channels cA = 2*pair+hf, cB = 2*pair+1-hf with compile-time kl:
//   step st<4 : ch = cA, kl = 16*st + e
//   step st>=4: ch = cB, kl = 16*(st-4)+8+e
// W2 is written with the same permutation (prep_w2), so Q fragments are
// computed directly in VGPRs.
//
// R9: 16 waves = (kg 0..7, ph 0..1) -- PIXEL-half split (not o-split):
// each wave = 8 ch x 32 px x 64 o (2 acc tiles). Products unique per
// (ch,px) -> per-CU product VALU = R4 level (half of R8's oh-dup), at
// 4 waves/SIMD. W2 read 2x per block (L2-hidden). W loads per-st to
// stay ~100 VGPR (cap 128 at launch_bounds(1024,4)).

typedef __attribute__((ext_vector_type(8))) short short8;
typedef __attribute__((ext_vector_type(16))) float f32x16;

#define NCH  64
#define NOUT 64

__device__ constexpr signed char TI[56] = {
  0,0,0,0,0,0,0,0,0,
  1,2,3,4,5,6,7,8,9,
  1,1,1,1,1,1,1,1,
  2,2,2,2,2,2,2,
  3,3,3,3,3,3,
  4,4,4,4,4,
  5,5,5,5,
  6,6,6,
  7,7,
  8,
  0,0};
__device__ constexpr signed char TJ[56] = {
  1,2,3,4,5,6,7,8,9,
  1,2,3,4,5,6,7,8,9,
  2,3,4,5,6,7,8,9,
  3,4,5,6,7,8,9,
  4,5,6,7,8,9,
  5,6,7,8,9,
  6,7,8,9,
  7,8,9,
  8,9,
  9,
  0,0};

__device__ __forceinline__ unsigned short f2bf(float f) {
  __hip_bfloat16 h = __float2bfloat16(f);
  unsigned short u;
  __builtin_memcpy(&u, &h, 2);
  return u;
}

// prep_w2 v3.1 (proven R7/R8): 256 blocks = (pair, o-octet). Coalesced
// float4 stage of F[og*8..+8, 2p:2p+2] into LDS, emit 112 short8 contiguous.
// W2 layout: pair*7168 + st*1024 + hf*512 + o*8 + e (shorts).
__global__ __launch_bounds__(256) void prep_w2(const float* __restrict__ F,
                                               const float* __restrict__ biases,
                                               unsigned short* __restrict__ W2) {
  const int pair = blockIdx.x >> 3, og = blockIdx.x & 7;
  __shared__ float Fl[8 * 200];     // [o8][chl*100 + i*10+j]
  __shared__ float bl[8];
  for (int t = threadIdx.x; t < 400; t += 256) {   // 400 float4 = 1600 floats
    int o8 = t / 50, r = t % 50;
    *(float4*)&Fl[o8 * 200 + r * 4] =
        *(const float4*)&F[(((size_t)(og * 8 + o8)) * NCH + 2 * pair) * 100 + r * 4];
  }
  if (threadIdx.x < 8) bl[threadIdx.x] = biases[og * 8 + threadIdx.x];
  __syncthreads();
  {
    int s = threadIdx.x;
    if (s < 112) {                  // o8 fast -> 8 consecutive short8 = 128B
      int o8 = s & 7, hf = (s >> 3) & 1, st = s >> 4;
      int chl = (st < 4) ? hf : 1 - hf;
      const float* base = &Fl[o8 * 200 + chl * 100];
      short8 v;
      #pragma unroll
      for (int e = 0; e < 8; ++e) {
        int kl = (st < 4) ? (16 * st + e) : (16 * (st - 4) + 8 + e);
        float w;
        if (kl < 54) {
          int i = TI[kl], j = TJ[kl];
          if (i == 0)      w = base[j] + base[j * 10];
          else if (i == j) w = base[i * 10 + j];
          else             w = base[i * 10 + j] + base[j * 10 + i];
        } else if (kl == 54) {
          w = base[0] + ((pair == 0 && chl == 0) ? bl[o8] : 0.f);
        } else {
          w = 0.f;
        }
        v[e] = (short)f2bf(w);
      }
      *(short8*)&W2[(size_t)pair * 7168 + (size_t)st * 1024 + hf * 512 +
                    (og * 8 + o8) * 8] = v;
    }
  }
}

// 256 blocks = (b, h); 1024 threads = 16 waves = (kg 0..7, ph 0..1).
// Wave (kg,ph): channels [8kg, 8kg+8), pixels [32ph, 32ph+32), o 0..63
// (2 acc tiles). LDS arena 139 KB (xs 55 KB / reduction 139 KB, aliased):
// 1 block/CU, 4 waves/SIMD at <=128 VGPR.
//   xs: channel ci -> dwords [ci*216, +216): 3 rows x 72 cols, x[w] at col
//       w+4, cols 0..3 / 68..71 zero halo.
//   R:  partials, row (kg*64+p) stride 68 dwords, o 0..63 contiguous.
__global__ __launch_bounds__(1024, 4) void poly2d_mfma(
    const float* __restrict__ x, const unsigned short* __restrict__ W2,
    float* __restrict__ out) {
  const int b = blockIdx.x >> 6, h = blockIdx.x & 63;
  const int tid = threadIdx.x;
  const int lane = tid & 63, wid = tid >> 6;
  const int kg = wid >> 1, ph = wid & 1;
  const int px = lane & 31, hf = lane >> 5;
  const int pxa = ph * 32 + px;            // this wave's absolute pixel

  __shared__ float smem[34816];   // 139264 B

  // ---- stage: wave wid stages channels [4*wid, 4*wid+4) ----
  {
    const int r = lane >> 4, q = lane & 15;          // lanes 0..47: body quads
    const size_t xbase = ((size_t)b * NCH + wid * 4) * 4096;
    #pragma unroll
    for (int i = 0; i < 4; ++i) {
      float* ch0 = &smem[(wid * 4 + i) * 216];
      if (lane < 48) {
        int hh = h + r - 1;
        bool ok = (unsigned)hh < 64u;
        int hcl = ok ? hh : 0;                       // clamped (safe) address
        float4 v = *(const float4*)&x[xbase + (size_t)i * 4096 + hcl * 64 + (q << 2)];
        if (!ok) v = make_float4(0.f, 0.f, 0.f, 0.f);
        *(float4*)&ch0[r * 72 + 4 + (q << 2)] = v;
      } else if (lane < 54) {
        int rr = (lane - 48) >> 1, side = lane & 1;  // zero halo cols
        *(float4*)&ch0[rr * 72 + (side ? 68 : 0)] = make_float4(0.f, 0.f, 0.f, 0.f);
      }
    }
  }
  __syncthreads();                 // staging shared within each kg pair

  f32x16 acc0, acc1;               // o 0..31 / o 32..63 at this wave's px
  #pragma unroll
  for (int r = 0; r < 16; ++r) { acc0[r] = 0.f; acc1[r] = 0.f; }

  #pragma unroll
  for (int stage = 0; stage < 4; ++stage) {
    const int cA = kg * 8 + stage * 2 + hf;   // channel of this lane-half
    const int cB = cA ^ 1;

    const float* rA = &smem[cA * 216 + pxa];
    const float* rB = &smem[cB * 216 + pxa];
    float sa[9], sb[9];
    #pragma unroll
    for (int r = 0; r < 3; ++r)
      #pragma unroll
      for (int d = 0; d < 3; ++d) {
        sa[r * 3 + d] = rA[r * 72 + 3 + d];
        sb[r * 3 + d] = rB[r * 72 + 3 + d];
      }

    const unsigned short* wb = W2 + (size_t)(kg * 4 + stage) * 7168 +
                               hf * 512 + px * 8;
    #pragma unroll
    for (int st = 0; st < 7; ++st) {
      const short8 w0 = *(const short8*)(wb + st * 1024);        // o 0..31
      const short8 w1 = *(const short8*)(wb + st * 1024 + 256);  // o 32..63
      short8 pk;
      #pragma unroll
      for (int e = 0; e < 8; ++e) {
        const int kl = (st < 4) ? (16 * st + e) : (16 * (st - 4) + 8 + e);
        const float* s = (st < 4) ? sa : sb;
        float v;
        if (kl == 55)      v = 0.f;
        else if (kl == 54) v = 1.f;
        else if (kl < 9)   v = s[kl];
        else if (kl < 18)  { float t = s[kl - 9]; v = t * t; }
        else               v = s[TI[kl] - 1] * s[TJ[kl] - 1];
        pk[e] = (short)f2bf(v);
      }
      acc0 = __builtin_amdgcn_mfma_f32_32x32x16_bf16(w0, pk, acc0, 0, 0, 0);
      acc1 = __builtin_amdgcn_mfma_f32_32x32x16_bf16(w1, pk, acc1, 0, 0, 0);
    }
  }

  // ---- single-round reduction over the 8 kg partials ----
  __syncthreads();               // all waves done with xs (arena reused as R)
  // D layout (m74/m101): col = lane&31 (= pixel), row = (r&3)+8*(r>>2)+4*hf
  // (= o_local). R(kg, p, o) at smem[(kg*64+p)*68 + o].
  {
    float* base = &smem[(kg * 64 + pxa) * 68];
    #pragma unroll
    for (int blk = 0; blk < 4; ++blk) {
      int ob = blk * 8 + 4 * hf;
      *(float4*)&base[ob]      = make_float4(acc0[blk*4], acc0[blk*4+1], acc0[blk*4+2], acc0[blk*4+3]);
      *(float4*)&base[ob + 32] = make_float4(acc1[blk*4], acc1[blk*4+1], acc1[blk*4+2], acc1[blk*4+3]);
    }
  }
  __syncthreads();
  {
    const int p = tid & 63, oq = tid >> 6;   // o-quad 0..15
    float4 sum = make_float4(0.f, 0.f, 0.f, 0.f);
    #pragma unroll
    for (int g = 0; g < 8; ++g) {
      float4 v = *(const float4*)&smem[(g * 64 + p) * 68 + oq * 4];
      sum.x += v.x; sum.y += v.y; sum.z += v.z; sum.w += v.w;
    }
    const size_t obase = (((size_t)b * NOUT + oq * 4) * 64 + h) * 64 + p;
    out[obase]          = sum.x;
    out[obase + 4096]   = sum.y;
    out[obase + 2*4096] = sum.z;
    out[obase + 3*4096] = sum.w;
  }
}

extern "C" void kernel_launch(void* const* d_in, const int* in_sizes, int n_in,
                              void* d_out, int out_size, void* d_ws, size_t ws_size,
                              hipStream_t stream) {
  const float* x       = (const float*)d_in[0];
  const float* filters = (const float*)d_in[1];
  const float* biases  = (const float*)d_in[2];
  float* out = (float*)d_out;
  unsigned short* W2 = (unsigned short*)d_ws;   // 229376 bf16 = 458752 B

  hipLaunchKernelGGL(prep_w2, dim3(256), dim3(256), 0, stream,
                     filters, biases, W2);
  hipLaunchKernelGGL(poly2d_mfma, dim3(256), dim3(1024), 0, stream,
                     x, W2, out);
}